// Round 19
// baseline (338.417 us; speedup 1.0000x reference)
//
// VQ layer (gumbel-softmax VQ) fused pipeline for MI355X (gfx950). Round 19.
// MEASUREMENT ROUND: every stage split into two half-M dispatches so the
// top-5 rocprof rows finally show K2 and K3 directly (never yet measured —
// R18 post-mortem found the cross-round subtraction estimates internally
// inconsistent). Kernels are byte-identical to R18 except for an M-offset
// parameter. Perf-neutral: 512-block GEMM grids = exactly 2 CU-rounds,
// XCD swizzle stays bijective (512%8==0).
//
//   K0  split_w : weights -> f16 hi/lo planes in ws (2 MB)
//   K1a/K1b gemm9<1,0>: hiddens = relu(X @ Wh^T + bh), rows [0,32K)/[32K,64K)
//   K2a/K2b gemm9<0,1>: logits = hiddens @ Wl^T + bl, same split
//   K3a/K3b argmax  : z = logits + gumbel(u); codes = cb[argmax z]
//
// f32-GEMM emulation: a = hi + lo*2^-12 (f16 split, lo scaled 2^12), 3 MFMAs:
// hi.hi -> acc_hh ; hi.lo + lo.hi -> acc_mx ; D = acc_hh + acc_mx*2^-12.

#include <hip/hip_runtime.h>
#include <hip/hip_fp16.h>

typedef _Float16 h16;
typedef __attribute__((ext_vector_type(8))) _Float16 h16x8;
typedef __attribute__((ext_vector_type(4))) float f32x4;

#define KDIM 512
#define NDIM 512
#define LO_SCALE 4096.0f
#define LO_INV   0.000244140625f

__device__ __forceinline__ void gload16(const void* g, void* l) {
  __builtin_amdgcn_global_load_lds((const __attribute__((address_space(1))) void*)g,
                                   (__attribute__((address_space(3))) void*)l, 16, 0, 0);
}

#define WAITV(n) asm volatile("s_waitcnt vmcnt(" #n ")" ::: "memory")
#define WAITL0() asm volatile("s_waitcnt lgkmcnt(0)" ::: "memory")
#define SB() __builtin_amdgcn_sched_barrier(0)

// ---------------- K0: split weights into f16 hi/lo planes ----------------
__global__ void split_w(const float* __restrict__ Wh, const float* __restrict__ Wl,
                        h16* __restrict__ WhHi, h16* __restrict__ WhLo,
                        h16* __restrict__ WlHi, h16* __restrict__ WlLo) {
  int i = blockIdx.x * 256 + threadIdx.x;          // 262144 elements
  float a = Wh[i];
  h16 h = (h16)a;
  WhHi[i] = h; WhLo[i] = (h16)((a - (float)h) * LO_SCALE);
  a = Wl[i];
  h = (h16)a;
  WlHi[i] = h; WlLo[i] = (h16)((a - (float)h) * LO_SCALE);
}

// ====== gemm9: C[256M x 128N] = A @ B^T (+bias), 8 waves, BK=32 ======
// Identical to R18 except bm0 (M-tile offset) parameter. 512 blocks/dispatch.
template <int AF32, int EPI>
__launch_bounds__(512, 1)
__global__ void gemm9_k(const void* __restrict__ Aptr, const void* __restrict__ AptrLo,
                        const h16* __restrict__ BHi, const h16* __restrict__ BLo,
                        const float* __restrict__ bias,
                        float* __restrict__ Cf32,
                        h16* __restrict__ OHi, h16* __restrict__ OLo,
                        int bm0) {
  __shared__ __align__(16) char lds[131072];
  const int tid = threadIdx.x;
  const int wave = tid >> 6, lane = tid & 63;
  const int wm = wave >> 1, wn = wave & 1;         // 4m x 2n waves, 64x64 each
  const int wg = (blockIdx.x & 7) * 64 + (blockIdx.x >> 3);  // XCD-chunked, 512 wgs
  const int bm = bm0 + (wg >> 2), bn = wg & 3;     // 128 M-tiles x 4 N-tiles
  const long arow0 = (long)bm * 256;
  const int brow0 = bn * 128;
  const int q = lane >> 4, rlo = lane & 15;

  f32x4 acc_hh[4][4] = {};
  f32x4 acc_mx[4][4] = {};
  f32x4 areg[2][4];                                // K1 only: 2 in-flight steps

  const int axrow = tid >> 1;
  const int akoff = (tid & 1) * 64;
  const int asw = (axrow & 7) << 4;

  auto aload = [&](f32x4 (&ar)[4], int kt) {
    const char* base = (const char*)Aptr + (arow0 + axrow) * 2048 + (long)kt * 128 + akoff;
#pragma unroll
    for (int i = 0; i < 4; ++i) ar[i] = *(const f32x4*)(base + i * 16);
  };
  auto awrite = [&](const f32x4 (&ar)[4], char* buf) {
    h16x8 hv[2], lv[2];
#pragma unroll
    for (int p = 0; p < 4; ++p)
#pragma unroll
      for (int e = 0; e < 4; ++e) {
        float a = ar[p][e];
        h16 h = (h16)a;
        hv[p >> 1][(p & 1) * 4 + e] = h;
        lv[p >> 1][(p & 1) * 4 + e] = (h16)((a - (float)h) * LO_SCALE);
      }
    int jb = (tid & 1) * 32;
#pragma unroll
    for (int p = 0; p < 2; ++p) {
      *(h16x8*)(buf + axrow * 128 + ((jb + p * 16) ^ asw)) = hv[p];
      *(h16x8*)(buf + axrow * 128 + ((jb + p * 16 + 64) ^ asw)) = lv[p];
    }
  };
  auto agld = [&](char* buf, int kt) {             // K2: A planes, 4 gload/thr
#pragma unroll
    for (int pass = 0; pass < 4; ++pass) {
      int p = pass * 8192 + wave * 1024 + lane * 16;
      int row = p >> 7;                            // 0..255
      int gs = ((p >> 4) & 7) ^ (row & 7);
      const char* sp = (gs & 4) ? (const char*)AptrLo : (const char*)Aptr;
      long off = (arow0 + row) * 1024 + (long)kt * 64 + (gs & 3) * 16;
      gload16(sp + off, buf + pass * 8192 + wave * 1024);
    }
  };
  auto bgld = [&](char* buf, int kt) {             // B planes, 2 gload/thr
#pragma unroll
    for (int pass = 0; pass < 2; ++pass) {
      int p = pass * 8192 + wave * 1024 + lane * 16;
      int row = p >> 7;                            // 0..127
      int gs = ((p >> 4) & 7) ^ (row & 7);
      const char* sp = (gs & 4) ? (const char*)BLo : (const char*)BHi;
      long off = (long)(brow0 + row) * 1024 + (long)kt * 64 + (gs & 3) * 16;
      gload16(sp + off, buf + 32768 + pass * 8192 + wave * 1024);
    }
  };

  // ---- prologue ----
  if (AF32) {
    aload(areg[0], 0);
    aload(areg[1], 1);
    WAITV(4);                                      // A0 landed
    awrite(areg[0], lds);
    bgld(lds, 0);
    WAITV(2);                                      // A1 landed (B0 flies)
    awrite(areg[1], lds + 49152);
    aload(areg[0], 2);                             // {B0·2, A2·4}
    bgld(lds + 49152, 1);                          // {B0·2, A2·4, B1·2} = 8
    WAITL0();
  } else {
    agld(lds, 0); bgld(lds, 0);
    agld(lds + 49152, 1); bgld(lds + 49152, 1);    // {S0·6, S1·6} = 12
  }

#pragma unroll
  for (int t = 0; t < 16; ++t) {
    if (AF32) {
      if (t <= 13) { WAITV(6); } else if (t == 14) { WAITV(2); } else { WAITV(0); }
    } else {
      if (t <= 14) { WAITV(6); } else { WAITV(0); }
    }
    SB();
    __builtin_amdgcn_s_barrier();                  // buf[t&1] fully staged
    SB();

    if (AF32 && t <= 12) aload(areg[(t + 3) & 1], t + 3);  // issue-early

    char* buf = lds + (t & 1) * 49152;
    h16x8 ah[4], al[4], bh[4], bl[4];
#pragma unroll
    for (int i = 0; i < 4; ++i) {
      int row = wm * 64 + i * 16 + rlo;
      int sw = (row & 7) << 4;
      ah[i] = *(const h16x8*)(buf + row * 128 + ((q * 16) ^ sw));
      al[i] = *(const h16x8*)(buf + row * 128 + ((q * 16 + 64) ^ sw));
      int rb = wn * 64 + i * 16 + rlo;
      int swb = (rb & 7) << 4;
      bh[i] = *(const h16x8*)(buf + 32768 + rb * 128 + ((q * 16) ^ swb));
      bl[i] = *(const h16x8*)(buf + 32768 + rb * 128 + ((q * 16 + 64) ^ swb));
    }
    __builtin_amdgcn_s_setprio(1);
#pragma unroll
    for (int i = 0; i < 4; ++i)
#pragma unroll
      for (int j = 0; j < 4; ++j)
        acc_hh[i][j] = __builtin_amdgcn_mfma_f32_16x16x32_f16(ah[i], bh[j], acc_hh[i][j], 0, 0, 0);
#pragma unroll
    for (int i = 0; i < 4; ++i)
#pragma unroll
      for (int j = 0; j < 4; ++j)
        acc_mx[i][j] = __builtin_amdgcn_mfma_f32_16x16x32_f16(ah[i], bl[j], acc_mx[i][j], 0, 0, 0);
#pragma unroll
    for (int i = 0; i < 4; ++i)
#pragma unroll
      for (int j = 0; j < 4; ++j)
        acc_mx[i][j] = __builtin_amdgcn_mfma_f32_16x16x32_f16(al[i], bh[j], acc_mx[i][j], 0, 0, 0);
    __builtin_amdgcn_s_setprio(0);

    WAITL0();                                      // our ds_reads of buf done
    SB();
    __builtin_amdgcn_s_barrier();                  // all waves done with buf
    SB();
    if (AF32) {
      if (t <= 12) {
        WAITV(6);                                  // A(t+2) landed
        awrite(areg[(t + 2) & 1], lds + (t & 1) * 49152);
        bgld(lds + (t & 1) * 49152, t + 2);
      } else if (t == 13) {
        WAITV(2);                                  // A15 landed (B14 flies)
        awrite(areg[1], lds + 49152);
        bgld(lds + 49152, 15);
      }
    } else {
      if (t + 2 < 16) { agld(lds + (t & 1) * 49152, t + 2); bgld(lds + (t & 1) * 49152, t + 2); }
    }
  }

  // ---- epilogue: repack [256][128] via LDS, coalesced 16B/lane stores ----
#pragma unroll
  for (int j = 0; j < 4; ++j) {
    int lcol = wn * 64 + j * 16 + rlo;
    float bv = bias[bn * 128 + lcol];
#pragma unroll
    for (int i = 0; i < 4; ++i)
#pragma unroll
      for (int r = 0; r < 4; ++r) {
        int lrow = wm * 64 + i * 16 + q * 4 + r;
        float v = acc_hh[i][j][r] + acc_mx[i][j][r] * LO_INV + bv;
        if (EPI == 0) {
          v = fmaxf(v, 0.0f);
          h16 h = (h16)v;
          h16 l = (h16)((v - (float)h) * LO_SCALE);
          unsigned uu = (unsigned)__builtin_bit_cast(unsigned short, h) |
                        ((unsigned)__builtin_bit_cast(unsigned short, l) << 16);
          *(unsigned*)(lds + lrow * 512 + lcol * 4) = uu;
        } else {
          *(float*)(lds + lrow * 512 + lcol * 4) = v;
        }
      }
  }
  __syncthreads();
#pragma unroll
  for (int pass = 0; pass < 16; ++pass) {
    int o = pass * 8192 + tid * 16;
    int lrow = o >> 9;                             // 512-B packed rows (0..255)
    int lcb = o & 511;
    if (EPI == 0) {
      uint4 d = *(const uint4*)(lds + o);
      uint2 hi, lo;
      hi.x = (d.x & 0xffffu) | (d.y << 16);
      hi.y = (d.z & 0xffffu) | (d.w << 16);
      lo.x = (d.x >> 16) | (d.y & 0xffff0000u);
      lo.y = (d.z >> 16) | (d.w & 0xffff0000u);
      long gb = (arow0 + lrow) * 1024 + bn * 256 + (lcb >> 1);
      *(uint2*)((char*)OHi + gb) = hi;
      *(uint2*)((char*)OLo + gb) = lo;
    } else {
      f32x4 d = *(const f32x4*)(lds + o);
      long gb = (arow0 + lrow) * 2048 + bn * 512 + lcb;
      *(f32x4*)((char*)Cf32 + gb) = d;
    }
  }
}

// ---------------- K3: gumbel + argmax + codebook gather ----------------
__global__ void k3_argmax_gather(const float* __restrict__ logits,
                                 const float* __restrict__ u,
                                 const float* __restrict__ cb,
                                 const int* __restrict__ testing,
                                 float* __restrict__ codes, long row0) {
  const int wave = threadIdx.x >> 6, lane = threadIdx.x & 63;
  const long row = row0 + (long)blockIdx.x * 4 + wave;  // one wave per row
  const f32x4* lrow = (const f32x4*)(logits + row * 512);
  const f32x4* urow = (const f32x4*)(u + row * 512);
  const int test = *testing;

  float best = -3.4e38f;
  int bi = 0;
#pragma unroll
  for (int h = 0; h < 2; ++h) {
    int c4 = h * 64 + lane;
    f32x4 z = lrow[c4];
    if (!test) {
      f32x4 uu = urow[c4];
#pragma unroll
      for (int t = 0; t < 4; ++t)
        z[t] += -logf(-logf(uu[t] + 1e-20f) + 1e-20f);
    }
#pragma unroll
    for (int t = 0; t < 4; ++t) {                  // in-lane ascending indices
      int c = c4 * 4 + t;
      if (z[t] > best) { best = z[t]; bi = c; }
    }
  }
#pragma unroll
  for (int off = 32; off; off >>= 1) {             // max with min-index ties
    float ob = __shfl_xor(best, off);
    int oi = __shfl_xor(bi, off);
    if (ob > best || (ob == best && oi < bi)) { best = ob; bi = oi; }
  }
  const f32x4* src = (const f32x4*)(cb + (long)bi * 512);
  f32x4* dst = (f32x4*)(codes + row * 512);
  dst[lane] = src[lane];
  dst[lane + 64] = src[lane + 64];
}

// ---------------- host ----------------
extern "C" void kernel_launch(void* const* d_in, const int* in_sizes, int n_in,
                              void* d_out, int out_size, void* d_ws, size_t ws_size,
                              hipStream_t stream) {
  const float* X = (const float*)d_in[0];
  const float* Wh = (const float*)d_in[1];
  const float* bh = (const float*)d_in[2];
  const float* Wl = (const float*)d_in[3];
  const float* bl = (const float*)d_in[4];
  const float* cb = (const float*)d_in[5];
  const float* u = (const float*)d_in[6];
  const int* testing = (const int*)d_in[7];

  float* logits = (float*)d_out;                   // 33554432 f32
  float* codes = logits + 33554432;                // 33554432 f32
  // hiddens hi/lo f16 planes live in the codes region until K3 overwrites it
  h16* Hhi = (h16*)codes;
  h16* Hlo = Hhi + 33554432;

  h16* WhHi = (h16*)d_ws;                          // 4 x 0.5 MB weight planes
  h16* WhLo = WhHi + 262144;
  h16* WlHi = WhLo + 262144;
  h16* WlLo = WlHi + 262144;

  split_w<<<dim3(1024), dim3(256), 0, stream>>>(Wh, Wl, WhHi, WhLo, WlHi, WlLo);

  // K1 split into two half-M dispatches (direct measurement of both halves)
  gemm9_k<1, 0><<<dim3(512), dim3(512), 0, stream>>>(
      (const void*)X, nullptr, WhHi, WhLo, bh, nullptr, Hhi, Hlo, 0);
  gemm9_k<1, 0><<<dim3(512), dim3(512), 0, stream>>>(
      (const void*)X, nullptr, WhHi, WhLo, bh, nullptr, Hhi, Hlo, 128);

  // K2 split into two half-M dispatches
  gemm9_k<0, 1><<<dim3(512), dim3(512), 0, stream>>>(
      (const void*)Hhi, (const void*)Hlo, WlHi, WlLo, bl, logits, nullptr, nullptr, 0);
  gemm9_k<0, 1><<<dim3(512), dim3(512), 0, stream>>>(
      (const void*)Hhi, (const void*)Hlo, WlHi, WlLo, bl, logits, nullptr, nullptr, 128);

  // K3 split into two half-M dispatches
  k3_argmax_gather<<<dim3(8192), dim3(256), 0, stream>>>(logits, u, cb, testing, codes, 0);
  k3_argmax_gather<<<dim3(8192), dim3(256), 0, stream>>>(logits, u, cb, testing, codes, 32768);
}